// Round 16
// baseline (90.938 us; speedup 1.0000x reference)
//
#include <hip/hip_runtime.h>
#include <math.h>

typedef unsigned short u16;
typedef unsigned int   u32;
typedef __attribute__((ext_vector_type(8))) short s8v;   // 8 bf16 (4 VGPRs)
typedef __attribute__((ext_vector_type(2))) unsigned int u32x2;
typedef __attribute__((ext_vector_type(4))) float f4v;   // MFMA C/D

#define NHEADS 12
#define SEQ 2048
#define CD 768
#define BB 2
#define QKVD 2304
#define CEXP 0.18033688f      // 0.125 * log2(e)
#define DEFER_THR 44.0f       // exp2(44*CEXP) ~ 245, bf16-safe

__device__ inline u16 f2bf(float f) {            // RNE fp32->bf16
    union { float f; unsigned u; } v; v.f = f;
    unsigned r = v.u + 0x7FFFu + ((v.u >> 16) & 1u);
    return (u16)(r >> 16);
}
__device__ inline u32 cvtpk_bf16(float lo, float hi) {
    u32 r;
    asm("v_cvt_pk_bf16_f32 %0, %1, %2" : "=v"(r) : "v"(lo), "v"(hi));
    return r;
}
__device__ inline float exp2_fast(float x) {     // native v_exp_f32: D = 2^S0
    float r;
    asm("v_exp_f32 %0, %1" : "=v"(r) : "v"(x));
    return r;
}
__device__ inline float max3f(float a, float b, float c) {
    float r;
    asm("v_max3_f32 %0, %1, %2, %3" : "=v"(r) : "v"(a), "v"(b), "v"(c));
    return r;
}

#define GLOAD16(SRC, DST) __builtin_amdgcn_global_load_lds(                 \
    (const __attribute__((address_space(1))) void*)(SRC),                   \
    (__attribute__((address_space(3))) void*)(DST), 16, 0, 0)

// XOR swizzle for row-major [R][64] bf16 tiles (128B rows): u16 index
#define SW(r, c) ((((r) << 6) + (c)) ^ (((r) & 7) << 3))

// ---------------------------------------------------------------------------
__global__ __launch_bounds__(256)
void cvt3_kernel(const float* __restrict__ a, u16* __restrict__ oa, int na,
                 const float* __restrict__ b, u16* __restrict__ ob, int nb,
                 const float* __restrict__ c, u16* __restrict__ oc) {
    const int i = (blockIdx.x * 256 + threadIdx.x) * 8;
    const float* src; u16* dst;
    if (i < na)           { src = a + i;            dst = oa + i; }
    else if (i < na + nb) { src = b + (i - na);     dst = ob + (i - na); }
    else                  { src = c + (i - na - nb); dst = oc + (i - na - nb); }
    const float4 x = *(const float4*)src;
    const float4 y = *(const float4*)(src + 4);
    s8v o;
    o[0] = (short)f2bf(x.x); o[1] = (short)f2bf(x.y);
    o[2] = (short)f2bf(x.z); o[3] = (short)f2bf(x.w);
    o[4] = (short)f2bf(y.x); o[5] = (short)f2bf(y.y);
    o[6] = (short)f2bf(y.z); o[7] = (short)f2bf(y.w);
    *(s8v*)dst = o;
}

// ---------------------------------------------------------------------------
// GEMM1 (fused): qkv = x @ w_qkv^T. 128x96 tile, BK=64, 4 waves, grid 768 =
// 32 row-tiles x 24 col-tiles = 3 blocks/CU exact. Q/K columns -> qkvb;
// V columns written TRANSPOSED straight to vT[bh][d][token] (vtrans fused).
// Each 16-lane col group lies wholly in one head's Q/K/V 64-block (192=12x16,
// no straddle) -> per-n wave-uniform predicate + vT base.
// ---------------------------------------------------------------------------
__global__ __launch_bounds__(256)
void gemm_qkv(const u16* __restrict__ A, const u16* __restrict__ W,
              u16* __restrict__ Cout, u16* __restrict__ vT,
              int M, int N, int K) {
    __shared__ u16 As[8192];           // [128][64] swizzled
    __shared__ u16 Bs[6144];           // [96][64] swizzled
    const int tid = threadIdx.x;
    const int l  = tid & 63, w = tid >> 6;
    const int wr = w >> 1, wc = w & 1;
    const int lq = l & 15, lg = l >> 4;

    const int fid = blockIdx.x;
    const int cpx = gridDim.x >> 3;            // 96
    const int swz = (fid & 7) * cpx + (fid >> 3);
    const int rowBase = (swz / 24) << 7;
    const int colBase = (swz % 24) * 96;

    f4v acc[4][3];
    #pragma unroll
    for (int m = 0; m < 4; ++m)
        #pragma unroll
        for (int n = 0; n < 3; ++n)
            #pragma unroll
            for (int r = 0; r < 4; ++r) acc[m][n][r] = 0.f;

    const int chunk = l & 7;
    const int r8    = l >> 3;

    for (int kb = 0; kb < K; kb += 64) {
        __syncthreads();
        #pragma unroll
        for (int j = 0; j < 4; ++j) {
            const int rowA = (w << 5) + (j << 3) + r8;       // 0..127
            const int sc   = (chunk ^ (rowA & 7)) << 3;
            GLOAD16(A + (size_t)(rowBase + rowA) * K + kb + sc,
                    &As[(w << 11) + (j << 9)]);
        }
        #pragma unroll
        for (int j = 0; j < 3; ++j) {
            const int rowB = w * 24 + (j << 3) + r8;         // 0..95
            const int sc   = (chunk ^ (rowB & 7)) << 3;
            GLOAD16(W + (size_t)(colBase + rowB) * K + kb + sc,
                    &Bs[w * 1536 + (j << 9)]);
        }
        __syncthreads();
        #pragma unroll
        for (int h = 0; h < 2; ++h) {
            const int kc = (h << 5) + (lg << 3);
            s8v af[4], bf[3];
            #pragma unroll
            for (int m = 0; m < 4; ++m)
                af[m] = *(const s8v*)&As[SW((wr << 6) + (m << 4) + lq, kc)];
            #pragma unroll
            for (int n = 0; n < 3; ++n)
                bf[n] = *(const s8v*)&Bs[SW(wc * 48 + (n << 4) + lq, kc)];
            #pragma unroll
            for (int m = 0; m < 4; ++m)
                #pragma unroll
                for (int n = 0; n < 3; ++n)
                    acc[m][n] = __builtin_amdgcn_mfma_f32_16x16x32_bf16(
                        af[m], bf[n], acc[m][n], 0, 0, 0);
        }
    }

    // epilogue: Q/K cols -> qkvb; V cols -> vT (transposed, token-contiguous)
    const int bb = rowBase >> 11;                  // batch (block within one b)
    const int tokBase = (rowBase & 2047) + (wr << 6);
    bool isV[3]; size_t vb[3];
    #pragma unroll
    for (int n = 0; n < 3; ++n) {
        const int c0 = colBase + wc * 48 + (n << 4);   // wave-uniform
        const int cm = c0 % 192;
        isV[n] = (cm >= 128);
        const int h = c0 / 192;
        vb[n] = ((size_t)(((bb * NHEADS + h) << 6) + (cm - 128) + lq)) * SEQ
              + tokBase;
    }
    #pragma unroll
    for (int m = 0; m < 4; ++m)
        #pragma unroll
        for (int r = 0; r < 4; ++r) {
            const int row = rowBase + (wr << 6) + (m << 4) + (lg << 2) + r;
            const int toff = (m << 4) + (lg << 2) + r;
            #pragma unroll
            for (int n = 0; n < 3; ++n) {
                const u16 v = f2bf(acc[m][n][r]);
                if (isV[n]) {
                    vT[vb[n] + toff] = v;
                } else {
                    const int col = colBase + wc * 48 + (n << 4) + lq;
                    Cout[(size_t)row * N + col] = v;
                }
            }
        }
}

// ---------------------------------------------------------------------------
// GEMM2: C = A @ W^T + bias, fp32 out. 64x64 tile, BK=64, 4 waves (2x2 of
// 32x32 quadrants, acc[2][2]). Grid 768 = 3 blocks/CU exact. (r15-verified.)
// ---------------------------------------------------------------------------
__global__ __launch_bounds__(256)
void gemm64_bf16(const u16* __restrict__ A, const u16* __restrict__ W,
                 const float* __restrict__ bias, float* __restrict__ C,
                 int M, int N, int K) {
    __shared__ u16 As[4096];   // [64][64] swizzled
    __shared__ u16 Bs[4096];
    const int tid = threadIdx.x;
    const int l  = tid & 63, w = tid >> 6;
    const int wr = w >> 1, wc = w & 1;
    const int lq = l & 15, lg = l >> 4;

    const int fid = blockIdx.x;
    const int cpx = gridDim.x >> 3;            // 96
    const int swz = (fid & 7) * cpx + (fid >> 3);
    const int rowBase = (swz / 12) << 6;
    const int colBase = (swz % 12) << 6;

    f4v acc[2][2];
    #pragma unroll
    for (int m = 0; m < 2; ++m)
        #pragma unroll
        for (int n = 0; n < 2; ++n)
            #pragma unroll
            for (int r = 0; r < 4; ++r) acc[m][n][r] = 0.f;

    const int chunk = l & 7;
    const int r8    = l >> 3;

    for (int kb = 0; kb < K; kb += 64) {
        __syncthreads();
        #pragma unroll
        for (int j = 0; j < 2; ++j) {
            const int rowA = (w << 4) + (j << 3) + r8;       // 0..63
            const int sc   = (chunk ^ (rowA & 7)) << 3;
            GLOAD16(A + (size_t)(rowBase + rowA) * K + kb + sc,
                    &As[(w << 10) + (j << 9)]);
            GLOAD16(W + (size_t)(colBase + rowA) * K + kb + sc,
                    &Bs[(w << 10) + (j << 9)]);
        }
        __syncthreads();
        #pragma unroll
        for (int h = 0; h < 2; ++h) {
            const int kc = (h << 5) + (lg << 3);
            s8v af[2], bf[2];
            #pragma unroll
            for (int m = 0; m < 2; ++m)
                af[m] = *(const s8v*)&As[SW((wr << 5) + (m << 4) + lq, kc)];
            #pragma unroll
            for (int n = 0; n < 2; ++n)
                bf[n] = *(const s8v*)&Bs[SW((wc << 5) + (n << 4) + lq, kc)];
            #pragma unroll
            for (int m = 0; m < 2; ++m)
                #pragma unroll
                for (int n = 0; n < 2; ++n)
                    acc[m][n] = __builtin_amdgcn_mfma_f32_16x16x32_bf16(
                        af[m], bf[n], acc[m][n], 0, 0, 0);
        }
    }

    #pragma unroll
    for (int m = 0; m < 2; ++m)
        #pragma unroll
        for (int r = 0; r < 4; ++r) {
            const int row = rowBase + (wr << 5) + (m << 4) + (lg << 2) + r;
            #pragma unroll
            for (int n = 0; n < 2; ++n) {
                const int col = colBase + (wc << 5) + (n << 4) + lq;
                C[(size_t)row * N + col] = acc[m][n][r] + bias[col];
            }
        }
}

// ---------------------------------------------------------------------------
// MFMA flash attention (r8/r15-verified; byte-identical).
// 8 waves, in-block KV-split, SINGLE-buffered K/V, 3 barriers/tile.
// Grid: 768 1-D, XCD-chunked swizzle. Group g = w>>2 owns keys [g*1024,+1024).
// LDS 48KB (3 blocks/CU, grid = 3/CU exactly, no tail).
// ---------------------------------------------------------------------------
__global__ __launch_bounds__(512)
void attn_mfma(const u16* __restrict__ qkv, const u16* __restrict__ vT,
               u16* __restrict__ outb) {
    __shared__ u16 SL[24576];
    const int tid = threadIdx.x;
    const int l = tid & 63, w = tid >> 6;     // w 0..7
    const int g = w >> 2, wl = w & 3;
    const int lq = l & 15, lg = l >> 4;

    const int fid = blockIdx.x;
    const int swz = (fid & 7) * 96 + (fid >> 3);
    const int q0 = (swz & 31) << 6;
    const int bh = swz >> 5;
    const int b = bh / NHEADS, h = bh % NHEADS;
    const u16* base = qkv + (size_t)b * SEQ * QKVD + h * 192;
    const u16* vbh  = vT + (size_t)bh * 64 * SEQ;
    u16* QP = SL + 16384;
    float* Of32 = (float*)(SL + 8192);        // [64][64] f32, aliases g1 K/V
    float* Msh  = (float*)(SL + 16384);       // [64], aliases QP (post-loop)
    float* Lsh  = Msh + 64;

    const int kv0 = g << 10;                  // group key base

    u32 koff[2], voff[2], kdst[2], vdst[2];
    {
        const int cs = l & 7;
        #pragma unroll
        for (int i = 0; i < 2; ++i) {
            const int row = (wl << 4) + (i << 3) + (l >> 3);
            koff[i] = (u32)(row * QKVD + 64 + ((cs ^ (row & 7)) << 3));
            voff[i] = (u32)(row * SEQ  +      ((cs ^ (row & 7)) << 3));
            kdst[i] = (u32)((g << 13) + (wl << 10) + (i << 9));
            vdst[i] = (u32)((g << 13) + 4096 + (wl << 10) + (i << 9));
        }
    }

    {   // prologue: stage tile 0 (K and V)
        const u16* sbK = base + (size_t)kv0 * QKVD;
        const u16* sbV = vbh + kv0;
        #pragma unroll
        for (int i = 0; i < 2; ++i) {
            GLOAD16(sbK + koff[i], &SL[kdst[i]]);
            GLOAD16(sbV + voff[i], &SL[vdst[i]]);
        }
    }
    {   // stage Q: 512 threads x 8 u16 covers [64][64]
        const s8v q1 = *(const s8v*)(base + (size_t)(q0 + l) * QKVD + (w << 3));
        *(s8v*)&QP[SW(l, w << 3)] = q1;
    }
    __syncthreads();               // Q visible; own tile-0 gloads drained
    s8v qf[2];
    #pragma unroll
    for (int h2 = 0; h2 < 2; ++h2)
        qf[h2] = *(const s8v*)&QP[SW((wl << 4) + lq, (h2 << 5) + (lg << 3))];

    s8v onesf;                       // denominator B-frag: col 0 <=> lq==0
    {
        const short o = (lq == 0) ? (short)0x3F80 : (short)0;
        #pragma unroll
        for (int e = 0; e < 8; ++e) onesf[e] = o;
    }
    f4v fz;                          // persistent zero C-operand
    #pragma unroll
    for (int r = 0; r < 4; ++r) fz[r] = 0.f;

    f4v oacc[4], osum;
    #pragma unroll
    for (int db = 0; db < 4; ++db)
        #pragma unroll
        for (int r = 0; r < 4; ++r) oacc[db][r] = 0.f;
    #pragma unroll
    for (int r = 0; r < 4; ++r) osum[r] = 0.f;
    float mrun = -3.0e38f;

    const u16* Kc = SL + (g << 13);
    const u16* Vc = Kc + 4096;

    for (int t = 0; t < 16; ++t) {
        __syncthreads();           // top: staged K,V visible

        float p[16];
        __builtin_amdgcn_s_setprio(1);
        #pragma unroll
        for (int kb = 0; kb < 4; ++kb) {
            const s8v k0 = *(const s8v*)&Kc[SW((kb << 4) + lq, (lg << 3))];
            const s8v k1 = *(const s8v*)&Kc[SW((kb << 4) + lq, 32 + (lg << 3))];
            f4v z;
            z = __builtin_amdgcn_mfma_f32_16x16x32_bf16(k0, qf[0], fz, 0, 0, 0);
            z = __builtin_amdgcn_mfma_f32_16x16x32_bf16(k1, qf[1], z, 0, 0, 0);
            #pragma unroll
            for (int r = 0; r < 4; ++r) p[(kb << 2) + r] = z[r];
        }
        __builtin_amdgcn_s_setprio(0);

        __syncthreads();           // all waves done reading K(t)
        if (t < 15) {              // stage K(t+1); hides under softmax+PV
            const u16* sbK = base + (size_t)(kv0 + (t + 1) * 64) * QKVD;
            #pragma unroll
            for (int i = 0; i < 2; ++i)
                GLOAD16(sbK + koff[i], &SL[kdst[i]]);
        }

        // defer-max softmax (local check only; cross-lane via ballot)
        float m1_ = max3f(p[0], p[1], p[2]);
        float m2_ = max3f(p[3], p[4], p[5]);
        float m3_ = max3f(p[6], p[7], p[8]);
        float m4_ = max3f(p[9], p[10], p[11]);
        float m5_ = max3f(p[12], p[13], p[14]);
        float mx  = fmaxf(max3f(m1_, m2_, p[15]), max3f(m3_, m4_, m5_));
        if (!__all(mx <= mrun + DEFER_THR)) {
            mx = fmaxf(mx, __shfl_xor(mx, 16));
            mx = fmaxf(mx, __shfl_xor(mx, 32));
            const float mn = fmaxf(mrun, mx);
            const float al = exp2_fast((mrun - mn) * CEXP);
            mrun = mn;
            float ar[4];
            #pragma unroll
            for (int r = 0; r < 4; ++r) ar[r] = __shfl(al, (lg << 2) + r);
            #pragma unroll
            for (int db = 0; db < 4; ++db)
                #pragma unroll
                for (int r = 0; r < 4; ++r) oacc[db][r] *= ar[r];
            #pragma unroll
            for (int r = 0; r < 4; ++r) osum[r] *= ar[r];
        }
        const float mC = -mrun * CEXP;
        #pragma unroll
        for (int i = 0; i < 16; ++i) p[i] = exp2_fast(fmaf(p[i], CEXP, mC));

        // P -> bf16 -> wave-private QP rows [w*16, w*16+16)
        #pragma unroll
        for (int kb = 0; kb < 4; ++kb) {
            u32x2 pw;
            pw[0] = cvtpk_bf16(p[(kb << 2) + 0], p[(kb << 2) + 1]);
            pw[1] = cvtpk_bf16(p[(kb << 2) + 2], p[(kb << 2) + 3]);
            *(u32x2*)&QP[SW((w << 4) + lq, (kb << 4) + (lg << 2))] = pw;
        }
        const s8v pf0 = *(const s8v*)&QP[SW((w << 4) + lq, (lg << 3))];
        const s8v pf1 = *(const s8v*)&QP[SW((w << 4) + lq, 32 + (lg << 3))];

        // PV (+ denominator via in-register ones-frag)
        __builtin_amdgcn_s_setprio(1);
        #pragma unroll
        for (int db = 0; db < 4; ++db) {
            const s8v v0 = *(const s8v*)&Vc[SW((db << 4) + lq, (lg << 3))];
            const s8v v1 = *(const s8v*)&Vc[SW((db << 4) + lq, 32 + (lg << 3))];
            oacc[db] = __builtin_amdgcn_mfma_f32_16x16x32_bf16(pf0, v0, oacc[db], 0, 0, 0);
            oacc[db] = __builtin_amdgcn_mfma_f32_16x16x32_bf16(pf1, v1, oacc[db], 0, 0, 0);
        }
        osum = __builtin_amdgcn_mfma_f32_16x16x32_bf16(pf0, onesf, osum, 0, 0, 0);
        osum = __builtin_amdgcn_mfma_f32_16x16x32_bf16(pf1, onesf, osum, 0, 0, 0);
        __builtin_amdgcn_s_setprio(0);

        __syncthreads();           // all waves done reading V(t)
        if (t < 15) {              // stage V(t+1)
            const u16* sbV = vbh + kv0 + (t + 1) * 64;
            #pragma unroll
            for (int i = 0; i < 2; ++i)
                GLOAD16(sbV + voff[i], &SL[vdst[i]]);
        }
    }

    // ---- merge group 1 -> group 0 through LDS ----
    if (g == 1) {
        if (lg == 0) Msh[(wl << 4) + lq] = mrun;
        if (lq == 0) {
            #pragma unroll
            for (int r = 0; r < 4; ++r)
                Lsh[(wl << 4) + (lg << 2) + r] = osum[r];
        }
        #pragma unroll
        for (int db = 0; db < 4; ++db)
            #pragma unroll
            for (int r = 0; r < 4; ++r)
                Of32[(((wl << 4) + (lg << 2) + r) << 6) + (db << 4) + lq] =
                    oacc[db][r];
    }
    __syncthreads();
    if (g == 0) {
        #pragma unroll
        for (int r = 0; r < 4; ++r) {
            const int rowq = (wl << 4) + (lg << 2) + r;
            const float m0r = __shfl(mrun, (lg << 2) + r);
            const float l0r = __shfl(osum[r], l & 48);
            const float m1r = Msh[rowq];
            const float l1r = Lsh[rowq];
            const float M   = fmaxf(m0r, m1r);
            const float w0  = exp2_fast((m0r - M) * CEXP);
            const float w1  = exp2_fast((m1r - M) * CEXP);
            const float inv = 1.f / (l0r * w0 + l1r * w1);
            const float a0 = w0 * inv, a1 = w1 * inv;
            const size_t row = (size_t)b * SEQ + q0 + rowq;
            #pragma unroll
            for (int db = 0; db < 4; ++db) {
                const float o1 = Of32[(rowq << 6) + (db << 4) + lq];
                outb[row * CD + h * 64 + (db << 4) + lq] =
                    f2bf(oacc[db][r] * a0 + o1 * a1);
            }
        }
    }
}

// ---------------------------------------------------------------------------
extern "C" void kernel_launch(void* const* d_in, const int* in_sizes, int n_in,
                              void* d_out, int out_size, void* d_ws, size_t ws_size,
                              hipStream_t stream) {
    const float* x     = (const float*)d_in[0];
    const float* w_qkv = (const float*)d_in[1];
    const float* w_mlp = (const float*)d_in[2];
    const float* b_mlp = (const float*)d_in[3];
    float* out = (float*)d_out;

    const int NX  = BB * SEQ * CD;        // 3,145,728
    const int NWQ = QKVD * CD;            // 1,769,472
    const int NWM = CD * CD;              //   589,824
    const int NQK = BB * SEQ * QKVD;      // 9,437,184
    const int NAT = BB * SEQ * CD;        // attn out
    u16* xb    = (u16*)d_ws;
    u16* wqkvb = xb + NX;
    u16* wmlpb = wqkvb + NWQ;
    u16* qkvb  = wmlpb + NWM;
    u16* attnb = qkvb + NQK;
    u16* vTb   = attnb + NAT;             // [24][64][2048]

    cvt3_kernel<<<(NX + NWQ + NWM) / 2048, 256, 0, stream>>>(
        x, xb, NX, w_qkv, wqkvb, NWQ, w_mlp, wmlpb);

    const int M = BB * SEQ;   // 4096
    {   // qkv = x @ w_qkv^T -> qkvb (Q/K) + vT (V, transposed), fused
        gemm_qkv<<<768, 256, 0, stream>>>(xb, wqkvb, qkvb, vTb, M, QKVD, CD);
    }
    {   // attention (r8-verified, 8 waves, KV-split, 3 blocks/CU)
        attn_mfma<<<768, 512, 0, stream>>>(qkvb, vTb, attnb);
    }
    {   // out = attn @ w_mlp^T + b  -> fp32 (64x64 tiles: 768 = 3/CU exact)
        gemm64_bf16<<<768, 256, 0, stream>>>(attnb, wmlpb, b_mlp, out,
                                             M, CD, CD);
    }
}

// Round 17
// 86.109 us; speedup vs baseline: 1.0561x; 1.0561x over previous
//
#include <hip/hip_runtime.h>
#include <math.h>

typedef unsigned short u16;
typedef unsigned int   u32;
typedef __attribute__((ext_vector_type(8))) short s8v;   // 8 bf16 (4 VGPRs)
typedef __attribute__((ext_vector_type(2))) unsigned int u32x2;
typedef __attribute__((ext_vector_type(4))) float f4v;   // MFMA C/D

#define NHEADS 12
#define SEQ 2048
#define CD 768
#define BB 2
#define QKVD 2304
#define CEXP 0.18033688f      // 0.125 * log2(e)
#define DEFER_THR 44.0f       // exp2(44*CEXP) ~ 245, bf16-safe

__device__ inline u16 f2bf(float f) {            // RNE fp32->bf16
    union { float f; unsigned u; } v; v.f = f;
    unsigned r = v.u + 0x7FFFu + ((v.u >> 16) & 1u);
    return (u16)(r >> 16);
}
__device__ inline u32 cvtpk_bf16(float lo, float hi) {
    u32 r;
    asm("v_cvt_pk_bf16_f32 %0, %1, %2" : "=v"(r) : "v"(lo), "v"(hi));
    return r;
}
__device__ inline float exp2_fast(float x) {     // native v_exp_f32: D = 2^S0
    float r;
    asm("v_exp_f32 %0, %1" : "=v"(r) : "v"(x));
    return r;
}
__device__ inline float max3f(float a, float b, float c) {
    float r;
    asm("v_max3_f32 %0, %1, %2, %3" : "=v"(r) : "v"(a), "v"(b), "v"(c));
    return r;
}

#define GLOAD16(SRC, DST) __builtin_amdgcn_global_load_lds(                 \
    (const __attribute__((address_space(1))) void*)(SRC),                   \
    (__attribute__((address_space(3))) void*)(DST), 16, 0, 0)

// XOR swizzle for row-major [R][64] bf16 tiles (128B rows): u16 index
#define SW(r, c) ((((r) << 6) + (c)) ^ (((r) & 7) << 3))

// ---------------------------------------------------------------------------
__global__ __launch_bounds__(256)
void cvt3_kernel(const float* __restrict__ a, u16* __restrict__ oa, int na,
                 const float* __restrict__ b, u16* __restrict__ ob, int nb,
                 const float* __restrict__ c, u16* __restrict__ oc) {
    const int i = (blockIdx.x * 256 + threadIdx.x) * 8;
    const float* src; u16* dst;
    if (i < na)           { src = a + i;            dst = oa + i; }
    else if (i < na + nb) { src = b + (i - na);     dst = ob + (i - na); }
    else                  { src = c + (i - na - nb); dst = oc + (i - na - nb); }
    const float4 x = *(const float4*)src;
    const float4 y = *(const float4*)(src + 4);
    s8v o;
    o[0] = (short)f2bf(x.x); o[1] = (short)f2bf(x.y);
    o[2] = (short)f2bf(x.z); o[3] = (short)f2bf(x.w);
    o[4] = (short)f2bf(y.x); o[5] = (short)f2bf(y.y);
    o[6] = (short)f2bf(y.z); o[7] = (short)f2bf(y.w);
    *(s8v*)dst = o;
}

// ---------------------------------------------------------------------------
// GEMM: C = A @ W^T (+bias). 128xBN tile, BK=64, 4 waves. 1-D grid,
// XCD-swizzled. (r8/r15-verified template; round 17 instantiates BN=96 for
// GEMM1 -> grid 768 = 3 blocks/CU exact, fixing the 576-block imbalance.)
// ---------------------------------------------------------------------------
template<int BN, int NBX, bool OUT_BF16, bool BIAS>
__global__ __launch_bounds__(256)
void gemm_bf16(const u16* __restrict__ A, const u16* __restrict__ W,
               const float* __restrict__ bias, void* __restrict__ Cout,
               int M, int N, int K) {
    constexpr int NF = BN / 32;
    __shared__ u16 As[8192];
    __shared__ u16 Bs[BN * 64];
    const int tid = threadIdx.x;
    const int l  = tid & 63, w = tid >> 6;
    const int wr = w >> 1, wc = w & 1;
    const int lq = l & 15, lg = l >> 4;

    const int fid = blockIdx.x;
    const int cpx = gridDim.x >> 3;
    const int swz = (fid & 7) * cpx + (fid >> 3);
    const int rowBase = (swz / NBX) << 7;
    const int colBase = (swz % NBX) * BN;

    f4v acc[4][NF];
    #pragma unroll
    for (int m = 0; m < 4; ++m)
        #pragma unroll
        for (int n = 0; n < NF; ++n)
            #pragma unroll
            for (int r = 0; r < 4; ++r) acc[m][n][r] = 0.f;

    const int chunk = l & 7;
    const int r8    = l >> 3;

    for (int kb = 0; kb < K; kb += 64) {
        __syncthreads();
        #pragma unroll
        for (int j = 0; j < 4; ++j) {
            const int rowA = (w << 5) + (j << 3) + r8;
            const int sc   = (chunk ^ (rowA & 7)) << 3;
            GLOAD16(A + (size_t)(rowBase + rowA) * K + kb + sc,
                    &As[(w << 11) + (j << 9)]);
        }
        #pragma unroll
        for (int j = 0; j < NF; ++j) {
            const int rowB = w * (BN / 4) + (j << 3) + r8;
            const int sc   = (chunk ^ (rowB & 7)) << 3;
            GLOAD16(W + (size_t)(colBase + rowB) * K + kb + sc,
                    &Bs[w * (BN * 16) + (j << 9)]);
        }
        __syncthreads();
        #pragma unroll
        for (int h = 0; h < 2; ++h) {
            const int kc = (h << 5) + (lg << 3);
            s8v af[4], bf[NF];
            #pragma unroll
            for (int m = 0; m < 4; ++m)
                af[m] = *(const s8v*)&As[SW((wr << 6) + (m << 4) + lq, kc)];
            #pragma unroll
            for (int n = 0; n < NF; ++n)
                bf[n] = *(const s8v*)&Bs[SW(wc * (BN / 2) + (n << 4) + lq, kc)];
            #pragma unroll
            for (int m = 0; m < 4; ++m)
                #pragma unroll
                for (int n = 0; n < NF; ++n)
                    acc[m][n] = __builtin_amdgcn_mfma_f32_16x16x32_bf16(
                        af[m], bf[n], acc[m][n], 0, 0, 0);
        }
    }

    #pragma unroll
    for (int m = 0; m < 4; ++m)
        #pragma unroll
        for (int r = 0; r < 4; ++r) {
            const int row = rowBase + (wr << 6) + (m << 4) + (lg << 2) + r;
            #pragma unroll
            for (int n = 0; n < NF; ++n) {
                const int col = colBase + wc * (BN / 2) + (n << 4) + lq;
                float v = acc[m][n][r];
                if (BIAS) v += bias[col];
                if (OUT_BF16) ((u16*)Cout)[(size_t)row * N + col] = f2bf(v);
                else        ((float*)Cout)[(size_t)row * N + col] = v;
            }
        }
}

// ---------------------------------------------------------------------------
// GEMM2: C = A @ W^T + bias, fp32 out. 64x64 tile, BK=64, 4 waves (2x2 of
// 32x32 quadrants, acc[2][2]). Grid 768 = 3 blocks/CU exact. (r15-verified.)
// ---------------------------------------------------------------------------
__global__ __launch_bounds__(256)
void gemm64_bf16(const u16* __restrict__ A, const u16* __restrict__ W,
                 const float* __restrict__ bias, float* __restrict__ C,
                 int M, int N, int K) {
    __shared__ u16 As[4096];   // [64][64] swizzled
    __shared__ u16 Bs[4096];
    const int tid = threadIdx.x;
    const int l  = tid & 63, w = tid >> 6;
    const int wr = w >> 1, wc = w & 1;
    const int lq = l & 15, lg = l >> 4;

    const int fid = blockIdx.x;
    const int cpx = gridDim.x >> 3;            // 96
    const int swz = (fid & 7) * cpx + (fid >> 3);
    const int rowBase = (swz / 12) << 6;
    const int colBase = (swz % 12) << 6;

    f4v acc[2][2];
    #pragma unroll
    for (int m = 0; m < 2; ++m)
        #pragma unroll
        for (int n = 0; n < 2; ++n)
            #pragma unroll
            for (int r = 0; r < 4; ++r) acc[m][n][r] = 0.f;

    const int chunk = l & 7;
    const int r8    = l >> 3;

    for (int kb = 0; kb < K; kb += 64) {
        __syncthreads();
        #pragma unroll
        for (int j = 0; j < 2; ++j) {
            const int rowA = (w << 4) + (j << 3) + r8;       // 0..63
            const int sc   = (chunk ^ (rowA & 7)) << 3;
            GLOAD16(A + (size_t)(rowBase + rowA) * K + kb + sc,
                    &As[(w << 10) + (j << 9)]);
            GLOAD16(W + (size_t)(colBase + rowA) * K + kb + sc,
                    &Bs[(w << 10) + (j << 9)]);
        }
        __syncthreads();
        #pragma unroll
        for (int h = 0; h < 2; ++h) {
            const int kc = (h << 5) + (lg << 3);
            s8v af[2], bf[2];
            #pragma unroll
            for (int m = 0; m < 2; ++m)
                af[m] = *(const s8v*)&As[SW((wr << 5) + (m << 4) + lq, kc)];
            #pragma unroll
            for (int n = 0; n < 2; ++n)
                bf[n] = *(const s8v*)&Bs[SW((wc << 5) + (n << 4) + lq, kc)];
            #pragma unroll
            for (int m = 0; m < 2; ++m)
                #pragma unroll
                for (int n = 0; n < 2; ++n)
                    acc[m][n] = __builtin_amdgcn_mfma_f32_16x16x32_bf16(
                        af[m], bf[n], acc[m][n], 0, 0, 0);
        }
    }

    #pragma unroll
    for (int m = 0; m < 2; ++m)
        #pragma unroll
        for (int r = 0; r < 4; ++r) {
            const int row = rowBase + (wr << 5) + (m << 4) + (lg << 2) + r;
            #pragma unroll
            for (int n = 0; n < 2; ++n) {
                const int col = colBase + (wc << 5) + (n << 4) + lq;
                C[(size_t)row * N + col] = acc[m][n][r] + bias[col];
            }
        }
}

// ---------------------------------------------------------------------------
// V-part transpose: qkvb [token][2304] (cols h*192+128..191) -> vT[bh][d][token]
// ---------------------------------------------------------------------------
__global__ __launch_bounds__(256)
void vtrans_kernel(const u16* __restrict__ qkvb, u16* __restrict__ vT) {
    __shared__ u16 T[64][66];
    const int bh = blockIdx.y;
    const int tt = blockIdx.x;
    const int b = bh / NHEADS, h = bh % NHEADS;
    const int r  = threadIdx.x >> 2;
    const int dc = (threadIdx.x & 3) << 4;
    const u16* src = qkvb + (size_t)(b * SEQ + tt * 64 + r) * QKVD
                   + h * 192 + 128 + dc;
    *(s8v*)&T[r][dc]     = *(const s8v*)(src);
    *(s8v*)&T[r][dc + 8] = *(const s8v*)(src + 8);
    __syncthreads();
    const int d  = threadIdx.x >> 2;
    const int tc = (threadIdx.x & 3) << 4;
    s8v o0, o1;
    #pragma unroll
    for (int j = 0; j < 8; ++j) {
        o0[j] = (short)T[tc + j][d];
        o1[j] = (short)T[tc + 8 + j][d];
    }
    u16* dst = vT + ((size_t)bh * 64 + d) * SEQ + tt * 64 + tc;
    *(s8v*)dst = o0;
    *(s8v*)(dst + 8) = o1;
}

// ---------------------------------------------------------------------------
// MFMA flash attention (r8/r15-verified; byte-identical).
// 8 waves, in-block KV-split, SINGLE-buffered K/V, 3 barriers/tile.
// Grid: 768 1-D, XCD-chunked swizzle. Group g = w>>2 owns keys [g*1024,+1024).
// LDS 48KB (3 blocks/CU, grid = 3/CU exactly, no tail).
// ---------------------------------------------------------------------------
__global__ __launch_bounds__(512)
void attn_mfma(const u16* __restrict__ qkv, const u16* __restrict__ vT,
               u16* __restrict__ outb) {
    __shared__ u16 SL[24576];
    const int tid = threadIdx.x;
    const int l = tid & 63, w = tid >> 6;     // w 0..7
    const int g = w >> 2, wl = w & 3;
    const int lq = l & 15, lg = l >> 4;

    const int fid = blockIdx.x;
    const int swz = (fid & 7) * 96 + (fid >> 3);
    const int q0 = (swz & 31) << 6;
    const int bh = swz >> 5;
    const int b = bh / NHEADS, h = bh % NHEADS;
    const u16* base = qkv + (size_t)b * SEQ * QKVD + h * 192;
    const u16* vbh  = vT + (size_t)bh * 64 * SEQ;
    u16* QP = SL + 16384;
    float* Of32 = (float*)(SL + 8192);        // [64][64] f32, aliases g1 K/V
    float* Msh  = (float*)(SL + 16384);       // [64], aliases QP (post-loop)
    float* Lsh  = Msh + 64;

    const int kv0 = g << 10;                  // group key base

    u32 koff[2], voff[2], kdst[2], vdst[2];
    {
        const int cs = l & 7;
        #pragma unroll
        for (int i = 0; i < 2; ++i) {
            const int row = (wl << 4) + (i << 3) + (l >> 3);
            koff[i] = (u32)(row * QKVD + 64 + ((cs ^ (row & 7)) << 3));
            voff[i] = (u32)(row * SEQ  +      ((cs ^ (row & 7)) << 3));
            kdst[i] = (u32)((g << 13) + (wl << 10) + (i << 9));
            vdst[i] = (u32)((g << 13) + 4096 + (wl << 10) + (i << 9));
        }
    }

    {   // prologue: stage tile 0 (K and V)
        const u16* sbK = base + (size_t)kv0 * QKVD;
        const u16* sbV = vbh + kv0;
        #pragma unroll
        for (int i = 0; i < 2; ++i) {
            GLOAD16(sbK + koff[i], &SL[kdst[i]]);
            GLOAD16(sbV + voff[i], &SL[vdst[i]]);
        }
    }
    {   // stage Q: 512 threads x 8 u16 covers [64][64]
        const s8v q1 = *(const s8v*)(base + (size_t)(q0 + l) * QKVD + (w << 3));
        *(s8v*)&QP[SW(l, w << 3)] = q1;
    }
    __syncthreads();               // Q visible; own tile-0 gloads drained
    s8v qf[2];
    #pragma unroll
    for (int h2 = 0; h2 < 2; ++h2)
        qf[h2] = *(const s8v*)&QP[SW((wl << 4) + lq, (h2 << 5) + (lg << 3))];

    s8v onesf;                       // denominator B-frag: col 0 <=> lq==0
    {
        const short o = (lq == 0) ? (short)0x3F80 : (short)0;
        #pragma unroll
        for (int e = 0; e < 8; ++e) onesf[e] = o;
    }
    f4v fz;                          // persistent zero C-operand
    #pragma unroll
    for (int r = 0; r < 4; ++r) fz[r] = 0.f;

    f4v oacc[4], osum;
    #pragma unroll
    for (int db = 0; db < 4; ++db)
        #pragma unroll
        for (int r = 0; r < 4; ++r) oacc[db][r] = 0.f;
    #pragma unroll
    for (int r = 0; r < 4; ++r) osum[r] = 0.f;
    float mrun = -3.0e38f;

    const u16* Kc = SL + (g << 13);
    const u16* Vc = Kc + 4096;

    for (int t = 0; t < 16; ++t) {
        __syncthreads();           // top: staged K,V visible

        float p[16];
        __builtin_amdgcn_s_setprio(1);
        #pragma unroll
        for (int kb = 0; kb < 4; ++kb) {
            const s8v k0 = *(const s8v*)&Kc[SW((kb << 4) + lq, (lg << 3))];
            const s8v k1 = *(const s8v*)&Kc[SW((kb << 4) + lq, 32 + (lg << 3))];
            f4v z;
            z = __builtin_amdgcn_mfma_f32_16x16x32_bf16(k0, qf[0], fz, 0, 0, 0);
            z = __builtin_amdgcn_mfma_f32_16x16x32_bf16(k1, qf[1], z, 0, 0, 0);
            #pragma unroll
            for (int r = 0; r < 4; ++r) p[(kb << 2) + r] = z[r];
        }
        __builtin_amdgcn_s_setprio(0);

        __syncthreads();           // all waves done reading K(t)
        if (t < 15) {              // stage K(t+1); hides under softmax+PV
            const u16* sbK = base + (size_t)(kv0 + (t + 1) * 64) * QKVD;
            #pragma unroll
            for (int i = 0; i < 2; ++i)
                GLOAD16(sbK + koff[i], &SL[kdst[i]]);
        }

        // defer-max softmax (local check only; cross-lane via ballot)
        float m1_ = max3f(p[0], p[1], p[2]);
        float m2_ = max3f(p[3], p[4], p[5]);
        float m3_ = max3f(p[6], p[7], p[8]);
        float m4_ = max3f(p[9], p[10], p[11]);
        float m5_ = max3f(p[12], p[13], p[14]);
        float mx  = fmaxf(max3f(m1_, m2_, p[15]), max3f(m3_, m4_, m5_));
        if (!__all(mx <= mrun + DEFER_THR)) {
            mx = fmaxf(mx, __shfl_xor(mx, 16));
            mx = fmaxf(mx, __shfl_xor(mx, 32));
            const float mn = fmaxf(mrun, mx);
            const float al = exp2_fast((mrun - mn) * CEXP);
            mrun = mn;
            float ar[4];
            #pragma unroll
            for (int r = 0; r < 4; ++r) ar[r] = __shfl(al, (lg << 2) + r);
            #pragma unroll
            for (int db = 0; db < 4; ++db)
                #pragma unroll
                for (int r = 0; r < 4; ++r) oacc[db][r] *= ar[r];
            #pragma unroll
            for (int r = 0; r < 4; ++r) osum[r] *= ar[r];
        }
        const float mC = -mrun * CEXP;
        #pragma unroll
        for (int i = 0; i < 16; ++i) p[i] = exp2_fast(fmaf(p[i], CEXP, mC));

        // P -> bf16 -> wave-private QP rows [w*16, w*16+16)
        #pragma unroll
        for (int kb = 0; kb < 4; ++kb) {
            u32x2 pw;
            pw[0] = cvtpk_bf16(p[(kb << 2) + 0], p[(kb << 2) + 1]);
            pw[1] = cvtpk_bf16(p[(kb << 2) + 2], p[(kb << 2) + 3]);
            *(u32x2*)&QP[SW((w << 4) + lq, (kb << 4) + (lg << 2))] = pw;
        }
        const s8v pf0 = *(const s8v*)&QP[SW((w << 4) + lq, (lg << 3))];
        const s8v pf1 = *(const s8v*)&QP[SW((w << 4) + lq, 32 + (lg << 3))];

        // PV (+ denominator via in-register ones-frag)
        __builtin_amdgcn_s_setprio(1);
        #pragma unroll
        for (int db = 0; db < 4; ++db) {
            const s8v v0 = *(const s8v*)&Vc[SW((db << 4) + lq, (lg << 3))];
            const s8v v1 = *(const s8v*)&Vc[SW((db << 4) + lq, 32 + (lg << 3))];
            oacc[db] = __builtin_amdgcn_mfma_f32_16x16x32_bf16(pf0, v0, oacc[db], 0, 0, 0);
            oacc[db] = __builtin_amdgcn_mfma_f32_16x16x32_bf16(pf1, v1, oacc[db], 0, 0, 0);
        }
        osum = __builtin_amdgcn_mfma_f32_16x16x32_bf16(pf0, onesf, osum, 0, 0, 0);
        osum = __builtin_amdgcn_mfma_f32_16x16x32_bf16(pf1, onesf, osum, 0, 0, 0);
        __builtin_amdgcn_s_setprio(0);

        __syncthreads();           // all waves done reading V(t)
        if (t < 15) {              // stage V(t+1)
            const u16* sbV = vbh + kv0 + (t + 1) * 64;
            #pragma unroll
            for (int i = 0; i < 2; ++i)
                GLOAD16(sbV + voff[i], &SL[vdst[i]]);
        }
    }

    // ---- merge group 1 -> group 0 through LDS ----
    if (g == 1) {
        if (lg == 0) Msh[(wl << 4) + lq] = mrun;
        if (lq == 0) {
            #pragma unroll
            for (int r = 0; r < 4; ++r)
                Lsh[(wl << 4) + (lg << 2) + r] = osum[r];
        }
        #pragma unroll
        for (int db = 0; db < 4; ++db)
            #pragma unroll
            for (int r = 0; r < 4; ++r)
                Of32[(((wl << 4) + (lg << 2) + r) << 6) + (db << 4) + lq] =
                    oacc[db][r];
    }
    __syncthreads();
    if (g == 0) {
        #pragma unroll
        for (int r = 0; r < 4; ++r) {
            const int rowq = (wl << 4) + (lg << 2) + r;
            const float m0r = __shfl(mrun, (lg << 2) + r);
            const float l0r = __shfl(osum[r], l & 48);
            const float m1r = Msh[rowq];
            const float l1r = Lsh[rowq];
            const float M   = fmaxf(m0r, m1r);
            const float w0  = exp2_fast((m0r - M) * CEXP);
            const float w1  = exp2_fast((m1r - M) * CEXP);
            const float inv = 1.f / (l0r * w0 + l1r * w1);
            const float a0 = w0 * inv, a1 = w1 * inv;
            const size_t row = (size_t)b * SEQ + q0 + rowq;
            #pragma unroll
            for (int db = 0; db < 4; ++db) {
                const float o1 = Of32[(rowq << 6) + (db << 4) + lq];
                outb[row * CD + h * 64 + (db << 4) + lq] =
                    f2bf(oacc[db][r] * a0 + o1 * a1);
            }
        }
    }
}

// ---------------------------------------------------------------------------
extern "C" void kernel_launch(void* const* d_in, const int* in_sizes, int n_in,
                              void* d_out, int out_size, void* d_ws, size_t ws_size,
                              hipStream_t stream) {
    const float* x     = (const float*)d_in[0];
    const float* w_qkv = (const float*)d_in[1];
    const float* w_mlp = (const float*)d_in[2];
    const float* b_mlp = (const float*)d_in[3];
    float* out = (float*)d_out;

    const int NX  = BB * SEQ * CD;        // 3,145,728
    const int NWQ = QKVD * CD;            // 1,769,472
    const int NWM = CD * CD;              //   589,824
    const int NQK = BB * SEQ * QKVD;      // 9,437,184
    const int NAT = BB * SEQ * CD;        // attn out
    u16* xb    = (u16*)d_ws;
    u16* wqkvb = xb + NX;
    u16* wmlpb = wqkvb + NWQ;
    u16* qkvb  = wmlpb + NWM;
    u16* attnb = qkvb + NQK;
    u16* vTb   = attnb + NAT;             // [24][64][2048]

    cvt3_kernel<<<(NX + NWQ + NWM) / 2048, 256, 0, stream>>>(
        x, xb, NX, w_qkv, wqkvb, NWQ, w_mlp, wmlpb);

    const int M = BB * SEQ;   // 4096
    {   // qkv = x @ w_qkv^T -> bf16 (128x96 tiles: grid 768 = 3/CU exact)
        gemm_bf16<96, 24, true, false><<<768, 256, 0, stream>>>(
            xb, wqkvb, nullptr, qkvb, M, QKVD, CD);
    }
    {   // V-part transpose
        dim3 grid(SEQ / 64, BB * NHEADS);
        vtrans_kernel<<<grid, 256, 0, stream>>>(qkvb, vTb);
    }
    {   // attention (r8-verified, 8 waves, KV-split, 3 blocks/CU)
        attn_mfma<<<768, 512, 0, stream>>>(qkvb, vTb, attnb);
    }
    {   // out = attn @ w_mlp^T + b  -> fp32 (64x64 tiles: 768 = 3/CU exact)
        gemm64_bf16<<<768, 256, 0, stream>>>(attnb, wmlpb, b_mlp, out,
                                             M, CD, CD);
    }
}